// Round 2
// baseline (104.139 us; speedup 1.0000x reference)
//
#include <hip/hip_runtime.h>
#include <math.h>

// Problem constants (fixed by the reference): N=50000, 8 types, dim_q=64, neurons=64.
#define NUM_TYPES 8
#define DIM 64          // dim_q == num_neurons == 64
#define SEG 8192        // per-type segment capacity (n_t ~ 6250, huge margin)
#define BA 256          // atoms per block (one per thread)

// ---------------------------------------------------------------------------
// Kernel 1: bucket atoms by type into 8 fixed segments of the workspace.
// Segments fill contiguously from 0 (atomicAdd base), -1 beyond -> mlp blocks
// past the fill level exit early. Also initializes out[0] = N * b1.
// ---------------------------------------------------------------------------
__global__ __launch_bounds__(256) void scatter_kernel(
    const int* __restrict__ Z, int* __restrict__ fill, int* __restrict__ sorted,
    const float* __restrict__ b1, float* __restrict__ out, int N)
{
    __shared__ int cnt[NUM_TYPES];
    __shared__ int base[NUM_TYPES];
    int tid = threadIdx.x;
    if (tid < NUM_TYPES) cnt[tid] = 0;
    __syncthreads();

    int i = blockIdx.x * 256 + tid;
    int z = 0, r = 0;
    bool valid = (i < N);
    if (valid) {
        z = Z[i];
        r = atomicAdd(&cnt[z], 1);   // LDS atomic, cheap
    }
    __syncthreads();
    if (tid < NUM_TYPES) base[tid] = atomicAdd(&fill[tid], cnt[tid]);
    __syncthreads();
    if (valid) {
        int p = base[z] + r;
        if (p < SEG) sorted[z * SEG + p] = i;  // guard cannot trigger at N=50000/8
    }
    if (i == 0) out[0] = (float)N * b1[0];
}

// ---------------------------------------------------------------------------
// Kernel 2: one atom per LANE, full 64-neuron range per lane.
// Block = 256 threads = 256 atoms of ONE type -> the W0[t][d][k] index is
// wave-uniform -> compiler emits s_load for W and the inner loop is
// v_fmac_f32 v_h, s_w, v_q : zero LDS, W reused 64x via the scalar operand.
// Q streams from global with a depth-2 float4 software prefetch.
// ---------------------------------------------------------------------------
__global__ __launch_bounds__(256, 1) void mlp_kernel(
    const float* __restrict__ desc, const float* __restrict__ W0,
    const float* __restrict__ b0, const float* __restrict__ W1,
    const int* __restrict__ sorted, float* __restrict__ out)
{
    const int t    = blockIdx.x >> 5;        // type (grid = 8 * 32)
    const int tile = blockIdx.x & 31;        // 256-atom tile within segment
    const int tid  = threadIdx.x;
    const int base = t * SEG + tile * BA;

    // Segments fill contiguously from 0, so first-slot<0 => whole tile empty.
    if (sorted[base] < 0) return;            // block-uniform exit

    const int  slot  = sorted[base + tid];
    const bool valid = (slot >= 0);
    // Invalid lanes read atom 0's row (same-address broadcast, free) and are
    // masked out in the epilogue. Keeps the inner loop branch-free.
    const float4* qp = (const float4*)(desc + (size_t)(valid ? slot : 0) * DIM);
    const float*  wp = W0 + t * (DIM * DIM); // wave-uniform

    float h[DIM];
    #pragma unroll
    for (int k = 0; k < DIM; ++k) h[k] = 0.f;

    // depth-2 prefetch of the 16 float4 q-chunks
    float4 q0 = qp[0];
    float4 q1 = qp[1];

    #pragma unroll 1
    for (int dv = 0; dv < 16; ++dv) {
        float4 cur = q0;
        q0 = q1;
        if (dv < 14) q1 = qp[dv + 2];
        float qa[4] = {cur.x, cur.y, cur.z, cur.w};
        #pragma unroll
        for (int j = 0; j < 4; ++j) {
            const float* wr = wp + (dv * 4 + j) * DIM;  // wave-uniform row
            const float qj = qa[j];
            #pragma unroll
            for (int k = 0; k < DIM; ++k)
                h[k] = fmaf(qj, wr[k], h[k]);           // v_fmac v, s, v
        }
    }

    // epilogue: tanh via exp2-based fast path, dot with W1, mask invalid lanes
    float e = 0.f;
    if (valid) {
        const float* b0r = b0 + t * DIM;   // wave-uniform
        const float* w1r = W1 + t * DIM;   // wave-uniform
        #pragma unroll
        for (int k = 0; k < DIM; ++k) {
            float x  = h[k] + b0r[k];
            float u  = __expf(2.0f * x);                       // e^{2x}
            float th = 1.0f - __fdividef(2.0f, u + 1.0f);      // tanh(x)
            e = fmaf(th, w1r[k], e);
        }
    }

    // wave reduce (64 lanes), cross-wave via LDS, one atomicAdd per block
    #pragma unroll
    for (int o = 32; o > 0; o >>= 1) e += __shfl_down(e, o, 64);
    __shared__ float wsum[4];
    if ((tid & 63) == 0) wsum[tid >> 6] = e;
    __syncthreads();
    if (tid == 0) atomicAdd(out, wsum[0] + wsum[1] + wsum[2] + wsum[3]);
}

// ---------------------------------------------------------------------------
extern "C" void kernel_launch(void* const* d_in, const int* in_sizes, int n_in,
                              void* d_out, int out_size, void* d_ws, size_t ws_size,
                              hipStream_t stream)
{
    const float* desc = (const float*)d_in[0];
    const float* W0   = (const float*)d_in[1];
    const float* b0   = (const float*)d_in[2];
    const float* W1   = (const float*)d_in[3];
    const float* b1   = (const float*)d_in[4];
    const int*   Z    = (const int*)d_in[5];
    const int N = in_sizes[5];

    // workspace: fill[8] at offset 0, sorted[8*8192] at offset 64 (~256.1 KB)
    int* fill   = (int*)d_ws;
    int* sorted = (int*)((char*)d_ws + 64);

    hipMemsetAsync(fill, 0, NUM_TYPES * sizeof(int), stream);
    hipMemsetAsync(sorted, 0xFF, NUM_TYPES * SEG * sizeof(int), stream);  // -1

    scatter_kernel<<<(N + 255) / 256, 256, 0, stream>>>(
        Z, fill, sorted, b1, (float*)d_out, N);

    mlp_kernel<<<NUM_TYPES * (SEG / BA), 256, 0, stream>>>(
        desc, W0, b0, W1, sorted, (float*)d_out);
}

// Round 3
// 86.897 us; speedup vs baseline: 1.1984x; 1.1984x over previous
//
#include <hip/hip_runtime.h>
#include <math.h>

// Problem constants (fixed by the reference): N=50000, 8 types, dim_q=64, neurons=64.
#define NUM_TYPES 8
#define DIM 64          // dim_q == num_neurons == 64
#define SEG 8192        // per-type segment capacity (n_t ~ 6250, huge margin)
#define BM 128          // atoms per tile
#define QS_STRIDE 132   // 128 + 4: keeps float4 alignment, breaks write conflicts

// ---------------------------------------------------------------------------
// Kernel 1: bucket atoms by type into 8 fixed segments of the workspace.
// fill[t] ends as the per-type count; mlp uses it for validity (no -1 poison
// of `sorted` needed -> one fewer memset dispatch).
// Also initializes out[0] = N * b1 (harness poisons d_out with 0xAA).
// ---------------------------------------------------------------------------
__global__ __launch_bounds__(256) void scatter_kernel(
    const int* __restrict__ Z, int* __restrict__ fill, int* __restrict__ sorted,
    const float* __restrict__ b1, float* __restrict__ out, int N)
{
    __shared__ int cnt[NUM_TYPES];
    __shared__ int base[NUM_TYPES];
    int tid = threadIdx.x;
    if (tid < NUM_TYPES) cnt[tid] = 0;
    __syncthreads();

    int i = blockIdx.x * 256 + tid;
    int z = 0, r = 0;
    bool valid = (i < N);
    if (valid) {
        z = Z[i];
        r = atomicAdd(&cnt[z], 1);   // LDS atomic, cheap
    }
    __syncthreads();
    if (tid < NUM_TYPES) base[tid] = atomicAdd(&fill[tid], cnt[tid]);
    __syncthreads();
    if (valid) {
        int p = base[z] + r;
        if (p < SEG) sorted[z * SEG + p] = i;  // guard cannot trigger at N=50000/8
    }
    if (i == 0) out[0] = (float)N * b1[0];
}

// ---------------------------------------------------------------------------
// Kernel 2: per-tile GEMM-style MLP (round-1 structure, validated).
// Tile = 128 atoms (one type) x 64 neurons; thread tile 8 atoms x 4 neurons.
// LDS: Qs[d][a] transposed (33 KB) + Ws[d][k] (16 KB) ~= 49 KB -> 3 blocks/CU.
// Epilogue tanh via __expf (validated exact-enough in round 2, absmax 0.0).
// ---------------------------------------------------------------------------
__global__ __launch_bounds__(256) void mlp_kernel(
    const float* __restrict__ desc, const float* __restrict__ W0,
    const float* __restrict__ b0, const float* __restrict__ W1,
    const int* __restrict__ sorted, const int* __restrict__ fill,
    float* __restrict__ out)
{
    __shared__ float Qs[DIM][QS_STRIDE];   // Qs[d][atom]
    __shared__ float Ws[DIM][DIM];         // Ws[d][k]  (same layout as W0[t])
    __shared__ int   slots[BM];
    __shared__ float b0s[DIM];
    __shared__ float W1s[DIM];
    __shared__ float wsum[4];

    const int t    = blockIdx.x >> 6;        // type  (grid = 8 * 64)
    const int tile = blockIdx.x & 63;        // tile within segment
    const int tid  = threadIdx.x;

    const int cnt_t = fill[t];               // same-address broadcast load
    const int a_lo  = tile * BM;             // first atom index of this tile
    if (a_lo >= cnt_t) return;               // empty tile (block-uniform exit)

    if (tid < BM)
        slots[tid] = (a_lo + tid < cnt_t) ? sorted[t * SEG + a_lo + tid] : -1;

    // --- stage W0[t] (4096 floats), b0[t], W1[t] ---
    {
        const float4* w0v = (const float4*)(W0 + t * DIM * DIM);
        float4* wsv = (float4*)&Ws[0][0];
        #pragma unroll
        for (int i = 0; i < 4; ++i) wsv[tid + i * 256] = w0v[tid + i * 256];
        if (tid < DIM) { b0s[tid] = b0[t * DIM + tid]; W1s[tid] = W1[t * DIM + tid]; }
    }
    __syncthreads();   // slots[] ready for the Q staging below

    // --- stage Q tile, transposed: 128 rows x 16 float4 = 2048 float4 ---
    #pragma unroll
    for (int it = 0; it < 8; ++it) {
        int f  = tid + it * 256;
        int a  = f >> 4;             // atom row (16 consecutive threads per row)
        int dv = (f & 15) << 2;      // starting d of the float4
        int idx = slots[a];
        float4 q = (idx >= 0) ? *(const float4*)(desc + (size_t)idx * DIM + dv)
                              : make_float4(0.f, 0.f, 0.f, 0.f);
        Qs[dv + 0][a] = q.x; Qs[dv + 1][a] = q.y;
        Qs[dv + 2][a] = q.z; Qs[dv + 3][a] = q.w;
    }
    __syncthreads();

    // --- compute: thread (ag,kg) owns atoms ag*8..+7, neurons kg*4..+3 ---
    const int ag = tid & 15;
    const int kg = tid >> 4;
    const int a0 = ag * 8;
    const int k0 = kg * 4;

    float acc[8][4] = {};
    #pragma unroll 4
    for (int d = 0; d < DIM; ++d) {
        float4 qa = *(const float4*)&Qs[d][a0];
        float4 qb = *(const float4*)&Qs[d][a0 + 4];
        float4 w  = *(const float4*)&Ws[d][k0];
        float q[8] = {qa.x, qa.y, qa.z, qa.w, qb.x, qb.y, qb.z, qb.w};
        #pragma unroll
        for (int i = 0; i < 8; ++i) {
            acc[i][0] += q[i] * w.x;
            acc[i][1] += q[i] * w.y;
            acc[i][2] += q[i] * w.z;
            acc[i][3] += q[i] * w.w;
        }
    }

    // --- epilogue: fast tanh, dot with W1, mask padded atoms, reduce ---
    float bk[4], wk[4];
    #pragma unroll
    for (int j = 0; j < 4; ++j) { bk[j] = b0s[k0 + j]; wk[j] = W1s[k0 + j]; }

    float e = 0.f;
    #pragma unroll
    for (int i = 0; i < 8; ++i) {
        if (slots[a0 + i] >= 0) {
            float s = 0.f;
            #pragma unroll
            for (int j = 0; j < 4; ++j) {
                float x  = acc[i][j] + bk[j];
                float u  = __expf(2.0f * x);                   // e^{2x}
                float th = 1.0f - __fdividef(2.0f, u + 1.0f);  // tanh(x)
                s = fmaf(th, wk[j], s);
            }
            e += s;
        }
    }

    // wave reduce (64 lanes), cross-wave via LDS, one atomicAdd per block
    #pragma unroll
    for (int o = 32; o > 0; o >>= 1) e += __shfl_down(e, o, 64);
    if ((tid & 63) == 0) wsum[tid >> 6] = e;
    __syncthreads();
    if (tid == 0) atomicAdd(out, wsum[0] + wsum[1] + wsum[2] + wsum[3]);
}

// ---------------------------------------------------------------------------
extern "C" void kernel_launch(void* const* d_in, const int* in_sizes, int n_in,
                              void* d_out, int out_size, void* d_ws, size_t ws_size,
                              hipStream_t stream)
{
    const float* desc = (const float*)d_in[0];
    const float* W0   = (const float*)d_in[1];
    const float* b0   = (const float*)d_in[2];
    const float* W1   = (const float*)d_in[3];
    const float* b1   = (const float*)d_in[4];
    const int*   Z    = (const int*)d_in[5];
    const int N = in_sizes[5];

    // workspace: fill[8] at offset 0, sorted[8*8192] at offset 64 (~256.1 KB)
    int* fill   = (int*)d_ws;
    int* sorted = (int*)((char*)d_ws + 64);

    hipMemsetAsync(fill, 0, NUM_TYPES * sizeof(int), stream);  // only small memset

    scatter_kernel<<<(N + 255) / 256, 256, 0, stream>>>(
        Z, fill, sorted, b1, (float*)d_out, N);

    mlp_kernel<<<NUM_TYPES * (SEG / BM), 256, 0, stream>>>(
        desc, W0, b0, W1, sorted, fill, (float*)d_out);
}